// Round 6
// baseline (579.971 us; speedup 1.0000x reference)
//
#include <hip/hip_runtime.h>
#include <hip/hip_cooperative_groups.h>
#include <math.h>

namespace cg = cooperative_groups;

#define N 4096
#define NFEAT 512
#define NHID 64
#define NCLASS 16
#define NHEADS 8
#define ALPHA 0.2f
#define NC 256   // chunks per head (16 rows each)

typedef __attribute__((ext_vector_type(8))) short bf16x8;
typedef __attribute__((ext_vector_type(4))) float f32x4;

__device__ inline unsigned short f2bf(float f) {
  unsigned u = __float_as_uint(f);
  unsigned r = u + 0x7fffu + ((u >> 16) & 1u);  // RNE
  return (unsigned short)(r >> 16);
}
__device__ inline float bf2f(unsigned short u) {
  return __uint_as_float(((unsigned)u) << 16);
}
__device__ inline unsigned mono(float f) {
  unsigned u = __float_as_uint(f);
  return (u & 0x80000000u) ? ~u : (u | 0x80000000u);
}

// ===========================================================================
// Cooperative kernel 1: pack -> gemm_h(+scores) -> rank(+split-k) ->
// chunksum -> chunkscan -> combine1. 512 blocks x 256 threads.
// ===========================================================================
__global__ __launch_bounds__(256) void k_coop1(
    const float* __restrict__ x, const float* __restrict__ Wh,
    const float* __restrict__ Wo, const float* __restrict__ ah,
    unsigned short* __restrict__ xb, unsigned short* __restrict__ Wt,
    unsigned short* __restrict__ Wt2, unsigned short* __restrict__ h1b,
    float* __restrict__ ssrc, float* __restrict__ sdst,
    float* __restrict__ ts, int* __restrict__ perm, int* __restrict__ ksp,
    float* __restrict__ csA, float* __restrict__ csB,
    float* __restrict__ csAz, float* __restrict__ csBz,
    unsigned short* __restrict__ xcb) {
  cg::grid_group grid = cg::this_grid();
  __shared__ __align__(16) char smem[16640];
  const int b = blockIdx.x, t = threadIdx.x;
  const int w = t >> 6, lane = t & 63, lr = lane & 15, kg = lane >> 4;

  // ---- phase 0: pack x (all blocks), Wh (blocks 0-63), Wo (block 64) ----
  {
#pragma unroll
    for (int rep = 0; rep < 4; ++rep) {
      int i = (((rep * 512 + b) << 8) + t) * 4;
      float4 v = *(const float4*)(x + i);
      ushort4 o;
      o.x = f2bf(v.x); o.y = f2bf(v.y); o.z = f2bf(v.z); o.w = f2bf(v.w);
      *(ushort4*)(xb + i) = o;
    }
    if (b < 64) {
      float(*ld)[65] = (float(*)[65])smem;
      int kt = b & 7, hd = b >> 3;
      const float* src = Wh + ((size_t)hd * NFEAT + kt * 64) * NHID;
      int r = t >> 2, c0 = (t & 3) * 16;
#pragma unroll
      for (int j = 0; j < 4; ++j) {
        float4 v = *(const float4*)(src + (size_t)r * NHID + c0 + j * 4);
        ld[r][c0 + j * 4 + 0] = v.x; ld[r][c0 + j * 4 + 1] = v.y;
        ld[r][c0 + j * 4 + 2] = v.z; ld[r][c0 + j * 4 + 3] = v.w;
      }
      __syncthreads();
      int n = t >> 2, kq = t & 3;
      unsigned short tmp[16];
#pragma unroll
      for (int j = 0; j < 16; ++j) tmp[j] = f2bf(ld[kq * 16 + j][n]);
      unsigned short* dst = Wt + ((size_t)hd * 64 + n) * NFEAT + kt * 64 + kq * 16;
      ((uint4*)dst)[0] = *(uint4*)tmp;
      ((uint4*)dst)[1] = *(uint4*)(tmp + 8);
    } else if (b == 64) {
      for (int e = t; e < NFEAT * NCLASS; e += 256) {
        int n = e & 15, k = e >> 4;
        Wt2[(size_t)n * NFEAT + k] = f2bf(Wo[(size_t)k * NCLASS + n]);
      }
    }
  }
  grid.sync();

  // ---- phase 1: MFMA gemm h (64-row tile/block) + fused scores ----
  {
    uint4(*Als)[4] = (uint4(*)[4])smem;           // 64 x 32 bf16
    uint4(*Bls)[4] = (uint4(*)[4])(smem + 4096);  // 64 x 32 bf16
    int hd = b >> 6, i0 = (b & 63) * 64;
    const unsigned short* xrow = xb + (size_t)i0 * NFEAT;
    const unsigned short* wrow = Wt + (size_t)hd * 64 * NFEAT;
    f32x4 acc[4];
#pragma unroll
    for (int nb = 0; nb < 4; ++nb) acc[nb] = (f32x4){0.f, 0.f, 0.f, 0.f};
    int ra = t >> 2, ua = t & 3;
    int arow_s = w * 16 + lr;
    for (int k0 = 0; k0 < NFEAT; k0 += 32) {
      uint4 qa = *(const uint4*)(xrow + (size_t)ra * NFEAT + k0 + ua * 8);
      uint4 qb = *(const uint4*)(wrow + (size_t)ra * NFEAT + k0 + ua * 8);
      __syncthreads();
      Als[ra][ua ^ (ra & 3)] = qa;
      Bls[ra][ua ^ (ra & 3)] = qb;
      __syncthreads();
      bf16x8 af = __builtin_bit_cast(bf16x8, Als[arow_s][kg ^ (arow_s & 3)]);
#pragma unroll
      for (int nb = 0; nb < 4; ++nb) {
        int col = nb * 16 + lr;
        bf16x8 bv = __builtin_bit_cast(bf16x8, Bls[col][kg ^ (col & 3)]);
        acc[nb] = __builtin_amdgcn_mfma_f32_16x16x32_bf16(af, bv, acc[nb], 0, 0, 0);
      }
    }
    float aS[4], aD[4];
#pragma unroll
    for (int nb = 0; nb < 4; ++nb) {
      aS[nb] = ah[hd * 128 + nb * 16 + lr];
      aD[nb] = ah[hd * 128 + 64 + nb * 16 + lr];
    }
    unsigned short* hrow = h1b + ((size_t)hd * N + i0) * NHID;
#pragma unroll
    for (int reg = 0; reg < 4; ++reg) {
      int row = w * 16 + kg * 4 + reg;
      float ps = 0.f, pd = 0.f;
#pragma unroll
      for (int nb = 0; nb < 4; ++nb) {
        hrow[(size_t)row * NHID + nb * 16 + lr] = f2bf(acc[nb][reg]);
        ps += acc[nb][reg] * aS[nb];
        pd += acc[nb][reg] * aD[nb];
      }
#pragma unroll
      for (int m = 1; m < 16; m <<= 1) { ps += __shfl_xor(ps, m); pd += __shfl_xor(pd, m); }
      if (lr == 0) {
        ssrc[(size_t)hd * N + i0 + row] = ps;
        sdst[(size_t)hd * N + i0 + row] = pd;
      }
    }
  }
  grid.sync();

  // ---- phase 2: ballot rank (sort scatter) + per-row split-k count ----
  {
    unsigned* skey = (unsigned*)smem;
    int hd = b >> 6, jt = b & 63;
    const float* th = sdst + (size_t)hd * N;
    for (int i = t; i < N; i += 256)
      skey[i] = (mono(th[i]) & 0xFFFFF000u) | (unsigned)i;
    __syncthreads();
    int jbase = jt * 64 + w * 16;
    unsigned kj[16], qk[16];
    int cnt[16], cq[16];
#pragma unroll
    for (int jj = 0; jj < 16; ++jj) {
      kj[jj] = skey[jbase + jj];
      qk[jj] = (mono(-ssrc[(size_t)hd * N + jbase + jj]) & 0xFFFFF000u) | 0xFFFu;
      cnt[jj] = 0; cq[jj] = 0;
    }
    for (int c = 0; c < N; c += 64) {
      unsigned key = skey[c + lane];
#pragma unroll
      for (int jj = 0; jj < 16; ++jj) {
        cnt[jj] += __popcll(__ballot(key < kj[jj]));
        cq[jj]  += __popcll(__ballot(key < qk[jj]));
      }
    }
    int myc = 0, myq = 0;
#pragma unroll
    for (int jj = 0; jj < 16; ++jj)
      if (lane == jj) { myc = cnt[jj]; myq = cq[jj]; }
    if (lane < 16) {
      int j = jbase + lane;
      ts[(size_t)hd * N + myc] = th[j];
      perm[(size_t)hd * N + myc] = j;
      ksp[(size_t)hd * N + j] = myq;
    }
  }
  grid.sync();

  // ---- phase 3: chunksum (16-row chunks, one wave each) ----
  {
    int hd = b >> 6, c = (b & 63) * 4 + w, r0 = c * 16;
    float tm = ts[(size_t)hd * N + N - 1];
    float sA = 0.f, sB = 0.f, sAz = 0.f, sBz = 0.f;
    for (int r = 0; r < 16; ++r) {
      float tv = ts[(size_t)hd * N + r0 + r];
      int p = perm[(size_t)hd * N + r0 + r];
      float eA = expf(ALPHA * (tv - tm));
      float eB = expf(tv - tm);
      float hv = bf2f(h1b[((size_t)hd * N + p) * NHID + lane]);
      sA += eA * hv; sB += eB * hv; sAz += eA; sBz += eB;
    }
    csA[((size_t)hd * NC + c) * NHID + lane] = sA;
    csB[((size_t)hd * NC + c) * NHID + lane] = sB;
    if (lane == 0) { csAz[hd * NC + c] = sAz; csBz[hd * NC + c] = sBz; }
  }
  grid.sync();

  // ---- phase 4: chunkscan (blocks 0-7; 4 groups x 64 chunks) ----
  if (b < 8) {
    float(*part)[64] = (float(*)[64])smem;
    float* partz = (float*)(smem + 1024);
    int hd = b, g = w;
    size_t cb0 = (size_t)hd * NC + g * 64;
    float s = 0.f, sz = 0.f;
    for (int j = 0; j < 64; ++j) {
      s += csA[(cb0 + j) * NHID + lane];
      if (lane == 0) sz += csAz[cb0 + j];
    }
    part[g][lane] = s;
    if (lane == 0) partz[g] = sz;
    __syncthreads();
    float base = 0.f, basez = 0.f;
    for (int g2 = 0; g2 < g; ++g2) {
      base += part[g2][lane];
      if (lane == 0) basez += partz[g2];
    }
    __syncthreads();
    float run = base, runz = basez;
    for (int j = 0; j < 64; ++j) {
      size_t o = (cb0 + j) * NHID + lane;
      float tmp = csA[o]; csA[o] = run; run += tmp;
      if (lane == 0) { float tz = csAz[cb0 + j]; csAz[cb0 + j] = runz; runz += tz; }
    }
    s = 0.f; sz = 0.f;
    for (int j = 0; j < 64; ++j) {
      s += csB[(cb0 + j) * NHID + lane];
      if (lane == 0) sz += csBz[cb0 + j];
    }
    part[g][lane] = s;
    if (lane == 0) partz[g] = sz;
    __syncthreads();
    base = 0.f; basez = 0.f;
    for (int g2 = g + 1; g2 < 4; ++g2) {
      base += part[g2][lane];
      if (lane == 0) basez += partz[g2];
    }
    run = base; runz = basez;
    for (int j = 63; j >= 0; --j) {
      size_t o = (cb0 + j) * NHID + lane;
      float tmp = csB[o]; csB[o] = run; run += tmp;
      if (lane == 0) { float tz = csBz[cb0 + j]; csBz[cb0 + j] = runz; runz += tz; }
    }
  }
  grid.sync();

  // ---- phase 5: combine1 (precomputed split-k; no search, no staging) ----
  {
    int hd = b >> 6, stripe = b & 63;
    float tm = ts[(size_t)hd * N + N - 1];
    for (int it = 0; it < 16; ++it) {
      int i = stripe * 64 + it * 4 + w;
      float s = ssrc[(size_t)hd * N + i];
      int k = ksp[(size_t)hd * N + i];
      int c = k >> 4; if (c > NC - 1) c = NC - 1;
      int c0 = c * 16;
      float v = s + tm;
      float m = fmaxf(v, ALPHA * v);
      float wA = expf(ALPHA * v - m), wB = expf(v - m);
      size_t cb = (size_t)hd * NC + c;
      float numA = csA[cb * NHID + lane];
      float numB = csB[cb * NHID + lane];
      float zA = csAz[cb], zB = csBz[cb];
      float tv16 = ts[(size_t)hd * N + c0 + lr];
      int pv16 = perm[(size_t)hd * N + c0 + lr];
#pragma unroll
      for (int r = 0; r < 16; ++r) {
        float tv = __shfl(tv16, r);
        int p = __shfl(pv16, r);
        float hv = bf2f(h1b[((size_t)hd * N + p) * NHID + lane]);
        bool isA = (c0 + r) < k;
        float e = expf((isA ? ALPHA : 1.f) * (tv - tm));
        if (isA) { numA += e * hv; zA += e; } else { numB += e * hv; zB += e; }
      }
      float Z = wA * zA + wB * zB;
      float f = (wA * numA + wB * numB) / Z;
      float e2 = f > 0.f ? f : expf(f) - 1.f;
      xcb[(size_t)i * (NHEADS * NHID) + hd * NHID + lane] = f2bf(e2);
    }
  }
}

// ===========================================================================
// Cooperative kernel 2: gemm2(+scores) -> rank2(+split-k) -> chunksum2 ->
// chunkscan2 -> combine2(+log_softmax). 256 blocks x 256 threads.
// ===========================================================================
__global__ __launch_bounds__(256) void k_coop2(
    const unsigned short* __restrict__ xcb, const unsigned short* __restrict__ Wt2,
    const float* __restrict__ ao, float* __restrict__ h2,
    float* __restrict__ ssrc, float* __restrict__ sdst,
    float* __restrict__ ts, int* __restrict__ perm, int* __restrict__ ksp,
    float* __restrict__ csA, float* __restrict__ csB,
    float* __restrict__ csAz, float* __restrict__ csBz,
    float* __restrict__ out) {
  cg::grid_group grid = cg::this_grid();
  __shared__ __align__(16) char smem[16640];
  const int b = blockIdx.x, t = threadIdx.x;
  const int w = t >> 6, lane = t & 63, lr = lane & 15, kg = lane >> 4;

  // ---- phase 0: gemm2 (wave 0, 16 rows/block) + scores ----
  if (w == 0) {
    int i0 = b * 16;
    f32x4 acc = (f32x4){0.f, 0.f, 0.f, 0.f};
    const unsigned short* arow = xcb + (size_t)(i0 + lr) * NFEAT;
    const unsigned short* brow = Wt2 + (size_t)lr * NFEAT;
#pragma unroll
    for (int k0 = 0; k0 < NFEAT; k0 += 32) {
      bf16x8 af = __builtin_bit_cast(bf16x8, *(const uint4*)(arow + k0 + kg * 8));
      bf16x8 bv = __builtin_bit_cast(bf16x8, *(const uint4*)(brow + k0 + kg * 8));
      acc = __builtin_amdgcn_mfma_f32_16x16x32_bf16(af, bv, acc, 0, 0, 0);
    }
    float aS = ao[lr], aD = ao[16 + lr];
#pragma unroll
    for (int reg = 0; reg < 4; ++reg) {
      int row = i0 + kg * 4 + reg;
      h2[(size_t)row * NCLASS + lr] = acc[reg];
      float ps = acc[reg] * aS, pd = acc[reg] * aD;
#pragma unroll
      for (int m = 1; m < 16; m <<= 1) { ps += __shfl_xor(ps, m); pd += __shfl_xor(pd, m); }
      if (lr == 0) { ssrc[row] = ps; sdst[row] = pd; }
    }
  }
  grid.sync();

  // ---- phase 1: rank2 + split-k (blocks 0-63) ----
  if (b < 64) {
    unsigned* skey = (unsigned*)smem;
    for (int i = t; i < N; i += 256)
      skey[i] = (mono(sdst[i]) & 0xFFFFF000u) | (unsigned)i;
    __syncthreads();
    int jbase = b * 64 + w * 16;
    unsigned kj[16], qk[16];
    int cnt[16], cq[16];
#pragma unroll
    for (int jj = 0; jj < 16; ++jj) {
      kj[jj] = skey[jbase + jj];
      qk[jj] = (mono(-ssrc[jbase + jj]) & 0xFFFFF000u) | 0xFFFu;
      cnt[jj] = 0; cq[jj] = 0;
    }
    for (int c = 0; c < N; c += 64) {
      unsigned key = skey[c + lane];
#pragma unroll
      for (int jj = 0; jj < 16; ++jj) {
        cnt[jj] += __popcll(__ballot(key < kj[jj]));
        cq[jj]  += __popcll(__ballot(key < qk[jj]));
      }
    }
    int myc = 0, myq = 0;
#pragma unroll
    for (int jj = 0; jj < 16; ++jj)
      if (lane == jj) { myc = cnt[jj]; myq = cq[jj]; }
    if (lane < 16) {
      int j = jbase + lane;
      ts[myc] = sdst[j];
      perm[myc] = j;
      ksp[j] = myq;
    }
  }
  grid.sync();

  // ---- phase 2: chunksum2 (1 chunk/block, wave 0, F=16) ----
  if (w == 0) {
    int c = b, r0 = c * 16;
    float tm = ts[N - 1];
    float sA = 0.f, sB = 0.f, sAz = 0.f, sBz = 0.f;
    for (int r = 0; r < 16; ++r) {
      float tv = ts[r0 + r];
      int p = perm[r0 + r];
      float eA = expf(ALPHA * (tv - tm)), eB = expf(tv - tm);
      float hv = (lane < 16) ? h2[(size_t)p * NCLASS + lane] : 0.f;
      sA += eA * hv; sB += eB * hv; sAz += eA; sBz += eB;
    }
    if (lane < 16) {
      csA[(size_t)c * NCLASS + lane] = sA;
      csB[(size_t)c * NCLASS + lane] = sB;
    }
    if (lane == 0) { csAz[c] = sAz; csBz[c] = sBz; }
  }
  grid.sync();

  // ---- phase 3: chunkscan2 (block 0; 16 groups x 16 chunks, F=16) ----
  if (b == 0) {
    float(*part)[16] = (float(*)[16])smem;
    float* partz = (float*)(smem + 1024);
    int cl = t & 15, g = t >> 4;
    size_t cb0 = (size_t)g * 16;
    float s = 0.f, sz = 0.f;
    for (int j = 0; j < 16; ++j) {
      s += csA[(cb0 + j) * NCLASS + cl];
      if (cl == 0) sz += csAz[cb0 + j];
    }
    part[g][cl] = s;
    if (cl == 0) partz[g] = sz;
    __syncthreads();
    float base = 0.f, basez = 0.f;
    for (int g2 = 0; g2 < g; ++g2) {
      base += part[g2][cl];
      if (cl == 0) basez += partz[g2];
    }
    __syncthreads();
    float run = base, runz = basez;
    for (int j = 0; j < 16; ++j) {
      size_t o = (cb0 + j) * NCLASS + cl;
      float tmp = csA[o]; csA[o] = run; run += tmp;
      if (cl == 0) { float tz = csAz[cb0 + j]; csAz[cb0 + j] = runz; runz += tz; }
    }
    s = 0.f; sz = 0.f;
    for (int j = 0; j < 16; ++j) {
      s += csB[(cb0 + j) * NCLASS + cl];
      if (cl == 0) sz += csBz[cb0 + j];
    }
    part[g][cl] = s;
    if (cl == 0) partz[g] = sz;
    __syncthreads();
    base = 0.f; basez = 0.f;
    for (int g2 = g + 1; g2 < 16; ++g2) {
      base += part[g2][cl];
      if (cl == 0) basez += partz[g2];
    }
    run = base; runz = basez;
    for (int j = 15; j >= 0; --j) {
      size_t o = (cb0 + j) * NCLASS + cl;
      float tmp = csB[o]; csB[o] = run; run += tmp;
      if (cl == 0) { float tz = csBz[cb0 + j]; csBz[cb0 + j] = runz; runz += tz; }
    }
  }
  grid.sync();

  // ---- phase 4: combine2 + ELU + log_softmax (16 rows/block) ----
  {
    int g = t >> 4, cl = t & 15;
    int i = b * 16 + g;
    float s = ssrc[i];
    int k = ksp[i];
    int c = k >> 4; if (c > NC - 1) c = NC - 1;
    int c0 = c * 16;
    float tm = ts[N - 1];
    float v = s + tm;
    float m = fmaxf(v, ALPHA * v);
    float wA = expf(ALPHA * v - m), wB = expf(v - m);
    float numA = csA[(size_t)c * NCLASS + cl];
    float numB = csB[(size_t)c * NCLASS + cl];
    float zA = csAz[c], zB = csBz[c];
    float tvg = ts[c0 + cl];
    int pvg = perm[c0 + cl];
#pragma unroll
    for (int r = 0; r < 16; ++r) {
      float tv = __shfl(tvg, r, 16);
      int p = __shfl(pvg, r, 16);
      float hv = h2[(size_t)p * NCLASS + cl];
      bool isA = (c0 + r) < k;
      float e = expf((isA ? ALPHA : 1.f) * (tv - tm));
      if (isA) { numA += e * hv; zA += e; } else { numB += e * hv; zB += e; }
    }
    float Z = wA * zA + wB * zB;
    float f = (wA * numA + wB * numB) / Z;
    float o = f > 0.f ? f : expf(f) - 1.f;
    float mx = o;
#pragma unroll
    for (int mk = 1; mk < 16; mk <<= 1) mx = fmaxf(mx, __shfl_xor(mx, mk, 16));
    float ex = expf(o - mx);
    float sum = ex;
#pragma unroll
    for (int mk = 1; mk < 16; mk <<= 1) sum += __shfl_xor(sum, mk, 16);
    out[(size_t)i * NCLASS + cl] = o - mx - logf(sum);
  }
}

// ---------------------------------------------------------------------------
extern "C" void kernel_launch(void* const* d_in, const int* in_sizes, int n_in,
                              void* d_out, int out_size, void* d_ws, size_t ws_size,
                              hipStream_t stream) {
  const float* x  = (const float*)d_in[0];
  const float* Wh = (const float*)d_in[1];
  const float* ah = (const float*)d_in[2];
  const float* Wo = (const float*)d_in[3];
  const float* ao = (const float*)d_in[4];
  float* outp = (float*)d_out;

  char* base = (char*)d_ws;
  size_t off = 0;
  auto alloc_f = [&](size_t n) -> float* {
    float* p = (float*)(base + off);
    off = (off + n * sizeof(float) + 255) & ~(size_t)255;
    return p;
  };
  auto alloc_i = [&](size_t n) -> int* {
    int* p = (int*)(base + off);
    off = (off + n * sizeof(int) + 255) & ~(size_t)255;
    return p;
  };
  auto alloc_u16 = [&](size_t n) -> unsigned short* {
    unsigned short* p = (unsigned short*)(base + off);
    off = (off + n * sizeof(unsigned short) + 255) & ~(size_t)255;
    return p;
  };

  unsigned short* xbf = alloc_u16((size_t)N * NFEAT);
  unsigned short* Wt  = alloc_u16((size_t)NHEADS * NHID * NFEAT);
  unsigned short* Wt2 = alloc_u16((size_t)NCLASS * NFEAT);
  unsigned short* h1b = alloc_u16((size_t)NHEADS * N * NHID);
  float* ssrc1 = alloc_f((size_t)NHEADS * N);
  float* sdst1 = alloc_f((size_t)NHEADS * N);
  float* ts1   = alloc_f((size_t)NHEADS * N);
  int*   perm1 = alloc_i((size_t)NHEADS * N);
  int*   ksp1  = alloc_i((size_t)NHEADS * N);
  float* csA1  = alloc_f((size_t)NHEADS * NC * NHID);
  float* csB1  = alloc_f((size_t)NHEADS * NC * NHID);
  float* csAz1 = alloc_f(NHEADS * NC);
  float* csBz1 = alloc_f(NHEADS * NC);
  unsigned short* xcb = alloc_u16((size_t)N * NHEADS * NHID);
  float* h2    = alloc_f((size_t)N * NCLASS);
  float* ssrc2 = alloc_f(N);
  float* sdst2 = alloc_f(N);
  float* ts2   = alloc_f(N);
  int*   perm2 = alloc_i(N);
  int*   ksp2  = alloc_i(N);
  float* csA2  = alloc_f((size_t)NC * NCLASS);
  float* csB2  = alloc_f((size_t)NC * NCLASS);
  float* csAz2 = alloc_f(NC);
  float* csBz2 = alloc_f(NC);

  if (off > ws_size) return;

  void* a1[] = {(void*)&x, (void*)&Wh, (void*)&Wo, (void*)&ah,
                (void*)&xbf, (void*)&Wt, (void*)&Wt2, (void*)&h1b,
                (void*)&ssrc1, (void*)&sdst1, (void*)&ts1, (void*)&perm1,
                (void*)&ksp1, (void*)&csA1, (void*)&csB1, (void*)&csAz1,
                (void*)&csBz1, (void*)&xcb};
  hipLaunchCooperativeKernel((const void*)k_coop1, dim3(512), dim3(256), a1, 0, stream);

  void* a2[] = {(void*)&xcb, (void*)&Wt2, (void*)&ao, (void*)&h2,
                (void*)&ssrc2, (void*)&sdst2, (void*)&ts2, (void*)&perm2,
                (void*)&ksp2, (void*)&csA2, (void*)&csB2, (void*)&csAz2,
                (void*)&csBz2, (void*)&outp};
  hipLaunchCooperativeKernel((const void*)k_coop2, dim3(256), dim3(256), a2, 0, stream);
}

// Round 8
// 236.747 us; speedup vs baseline: 2.4498x; 2.4498x over previous
//
#include <hip/hip_runtime.h>
#include <math.h>

#define N 4096
#define NFEAT 512
#define NHID 64
#define NCLASS 16
#define NHEADS 8
#define ALPHA 0.2f
#define NC 256   // chunks per head (16 rows each)

typedef __attribute__((ext_vector_type(8))) short bf16x8;
typedef __attribute__((ext_vector_type(4))) float f32x4;

__device__ inline unsigned short f2bf(float f) {
  unsigned u = __float_as_uint(f);
  unsigned r = u + 0x7fffu + ((u >> 16) & 1u);  // RNE
  return (unsigned short)(r >> 16);
}
__device__ inline float bf2f(unsigned short u) {
  return __uint_as_float(((unsigned)u) << 16);
}
__device__ inline unsigned mono(float f) {
  unsigned u = __float_as_uint(f);
  return (u & 0x80000000u) ? ~u : (u | 0x80000000u);
}

// ---------------------------------------------------------------------------
// P0: pack. blocks [0,2048): x->bf16; [2048,2112): Wt=bf16(Wh^T); 2112: Wt2.
// ---------------------------------------------------------------------------
__global__ __launch_bounds__(256) void k_pack(const float* __restrict__ x,
                                              const float* __restrict__ Wh,
                                              const float* __restrict__ Wo,
                                              unsigned short* __restrict__ xb,
                                              unsigned short* __restrict__ Wt,
                                              unsigned short* __restrict__ Wt2) {
  int b = blockIdx.x;
  if (b < 2048) {
    int i = (b * 256 + threadIdx.x) * 4;
    float4 v = *(const float4*)(x + i);
    ushort4 o;
    o.x = f2bf(v.x); o.y = f2bf(v.y); o.z = f2bf(v.z); o.w = f2bf(v.w);
    *(ushort4*)(xb + i) = o;
  } else if (b < 2112) {
    int idx = b - 2048;
    int kt = idx & 7, hd = idx >> 3;
    __shared__ float ld[64][65];
    const float* src = Wh + ((size_t)hd * NFEAT + kt * 64) * NHID;
    int r = threadIdx.x >> 2, c0 = (threadIdx.x & 3) * 16;
#pragma unroll
    for (int j = 0; j < 4; ++j) {
      float4 v = *(const float4*)(src + (size_t)r * NHID + c0 + j * 4);
      ld[r][c0 + j * 4 + 0] = v.x; ld[r][c0 + j * 4 + 1] = v.y;
      ld[r][c0 + j * 4 + 2] = v.z; ld[r][c0 + j * 4 + 3] = v.w;
    }
    __syncthreads();
    int n = threadIdx.x >> 2, kq = threadIdx.x & 3;
    unsigned short tmp[16];
#pragma unroll
    for (int j = 0; j < 16; ++j) tmp[j] = f2bf(ld[kq * 16 + j][n]);
    unsigned short* dst = Wt + ((size_t)hd * 64 + n) * NFEAT + kt * 64 + kq * 16;
    ((uint4*)dst)[0] = *(uint4*)tmp;
    ((uint4*)dst)[1] = *(uint4*)(tmp + 8);
  } else {
    for (int e = threadIdx.x; e < NFEAT * NCLASS; e += 256) {
      int n = e & 15, k = e >> 4;
      Wt2[(size_t)n * NFEAT + k] = f2bf(Wo[(size_t)k * NCLASS + n]);
    }
  }
}

// ---------------------------------------------------------------------------
// K1: MFMA bf16 GEMM h = x @ Wh per head, 128x64 tile, 4 waves, fused scores.
// h stored bf16.
// ---------------------------------------------------------------------------
__global__ __launch_bounds__(256) void k_gemm_h(const unsigned short* __restrict__ xb,
                                                const unsigned short* __restrict__ Wt,
                                                const float* __restrict__ ah,
                                                unsigned short* __restrict__ h1b,
                                                float* __restrict__ ssrc,
                                                float* __restrict__ sdst) {
  const int hd = blockIdx.y;
  const int i0 = blockIdx.x * 128;
  const int t = threadIdx.x;
  const int w = t >> 6, lane = t & 63;
  const int lr = lane & 15, kg = lane >> 4;
  const int wm = (w & 1) * 64, wn = (w >> 1) * 32;
  __shared__ uint4 Als[128][4];
  __shared__ uint4 Bls[64][4];
  __shared__ float sredS[128][2];
  __shared__ float sredD[128][2];
  const unsigned short* xrow = xb + (size_t)i0 * NFEAT;
  const unsigned short* wrow = Wt + (size_t)hd * 64 * NFEAT;

  f32x4 acc[4][2];
#pragma unroll
  for (int a = 0; a < 4; ++a)
#pragma unroll
    for (int b = 0; b < 2; ++b) acc[a][b] = (f32x4){0.f, 0.f, 0.f, 0.f};

  const int ra = t >> 1, ua = (t & 1) * 2;
  const int rb = t >> 2, ub = t & 3;
  for (int k0 = 0; k0 < NFEAT; k0 += 32) {
    uint4 qa0 = *(const uint4*)(xrow + (size_t)ra * NFEAT + k0 + ua * 8);
    uint4 qa1 = *(const uint4*)(xrow + (size_t)ra * NFEAT + k0 + ua * 8 + 8);
    uint4 qb  = *(const uint4*)(wrow + (size_t)rb * NFEAT + k0 + ub * 8);
    Als[ra][(ua) ^ (ra & 3)] = qa0;
    Als[ra][(ua + 1) ^ (ra & 3)] = qa1;
    Bls[rb][ub ^ (rb & 3)] = qb;
    __syncthreads();
    bf16x8 af[4], bfv[2];
#pragma unroll
    for (int mb = 0; mb < 4; ++mb) {
      int row = wm + mb * 16 + lr;
      af[mb] = __builtin_bit_cast(bf16x8, Als[row][kg ^ (row & 3)]);
    }
#pragma unroll
    for (int nb = 0; nb < 2; ++nb) {
      int col = wn + nb * 16 + lr;
      bfv[nb] = __builtin_bit_cast(bf16x8, Bls[col][kg ^ (col & 3)]);
    }
#pragma unroll
    for (int mb = 0; mb < 4; ++mb)
#pragma unroll
      for (int nb = 0; nb < 2; ++nb)
        acc[mb][nb] = __builtin_amdgcn_mfma_f32_16x16x32_bf16(af[mb], bfv[nb], acc[mb][nb], 0, 0, 0);
    __syncthreads();
  }

  unsigned short* hout = h1b + ((size_t)hd * N + i0) * NHID;
#pragma unroll
  for (int mb = 0; mb < 4; ++mb)
#pragma unroll
    for (int nb = 0; nb < 2; ++nb) {
      int rbase = wm + mb * 16 + kg * 4;
      int col = wn + nb * 16 + lr;
#pragma unroll
      for (int reg = 0; reg < 4; ++reg)
        hout[(size_t)(rbase + reg) * NHID + col] = f2bf(acc[mb][nb][reg]);
    }

  float aS[2], aD[2];
#pragma unroll
  for (int nb = 0; nb < 2; ++nb) {
    aS[nb] = ah[hd * 128 + wn + nb * 16 + lr];
    aD[nb] = ah[hd * 128 + 64 + wn + nb * 16 + lr];
  }
#pragma unroll
  for (int mb = 0; mb < 4; ++mb)
#pragma unroll
    for (int reg = 0; reg < 4; ++reg) {
      float ps = acc[mb][0][reg] * aS[0] + acc[mb][1][reg] * aS[1];
      float pd = acc[mb][0][reg] * aD[0] + acc[mb][1][reg] * aD[1];
#pragma unroll
      for (int m = 1; m < 16; m <<= 1) { ps += __shfl_xor(ps, m); pd += __shfl_xor(pd, m); }
      if (lr == 0) {
        int rl = wm + mb * 16 + kg * 4 + reg;
        sredS[rl][w >> 1] = ps;
        sredD[rl][w >> 1] = pd;
      }
    }
  __syncthreads();
  if (t < 128) {
    ssrc[(size_t)hd * N + i0 + t] = sredS[t][0] + sredS[t][1];
    sdst[(size_t)hd * N + i0 + t] = sredD[t][0] + sredD[t][1];
  }
}

// ---------------------------------------------------------------------------
// K4: ballot rank + per-row split-k. u32 keys (monotone 20 bits | index).
// Wave owns 16 j's; cnt via popc(ballot). ksp[j] = #keys < monokey(-ssrc[j]).
// ---------------------------------------------------------------------------
__global__ __launch_bounds__(256) void k_rank(const float* __restrict__ t,
                                              const float* __restrict__ ssrc,
                                              float* __restrict__ ts,
                                              int* __restrict__ perm,
                                              int* __restrict__ ksp) {
  int hd = blockIdx.y;
  const float* th = t + (size_t)hd * N;
  __shared__ unsigned skey[N];
  int tid = threadIdx.x;
  for (int i = tid; i < N; i += 256)
    skey[i] = (mono(th[i]) & 0xFFFFF000u) | (unsigned)i;
  __syncthreads();
  int wv = tid >> 6, lane = tid & 63;
  int jbase = blockIdx.x * 64 + wv * 16;
  unsigned kj[16], qk[16];
  int cnt[16], cq[16];
#pragma unroll
  for (int jj = 0; jj < 16; ++jj) {
    kj[jj] = skey[jbase + jj];
    qk[jj] = (mono(-ssrc[(size_t)hd * N + jbase + jj]) & 0xFFFFF000u) | 0xFFFu;
    cnt[jj] = 0; cq[jj] = 0;
  }
  for (int c = 0; c < N; c += 64) {
    unsigned key = skey[c + lane];
#pragma unroll
    for (int jj = 0; jj < 16; ++jj) {
      cnt[jj] += __popcll(__ballot(key < kj[jj]));
      cq[jj]  += __popcll(__ballot(key < qk[jj]));
    }
  }
  int myc = 0, myq = 0;
#pragma unroll
  for (int jj = 0; jj < 16; ++jj)
    if (lane == jj) { myc = cnt[jj]; myq = cq[jj]; }
  if (lane < 16) {
    int j = jbase + lane;
    ts[(size_t)hd * N + myc] = th[j];
    perm[(size_t)hd * N + myc] = j;
    ksp[(size_t)hd * N + j] = myq;
  }
}

// ---------------------------------------------------------------------------
// K5: fused chunksum + scan, layer 1. 8 blocks x 1024 thr. Wave w holds its
// 16 chunk-sums in registers; one barrier; in-register scan; write scanned
// csA (prefix-before-chunk) / csB (suffix-after-chunk).
// ---------------------------------------------------------------------------
__global__ __launch_bounds__(1024) void k_sumscan1(const float* __restrict__ ts,
                                                   const int* __restrict__ perm,
                                                   const unsigned short* __restrict__ h1b,
                                                   float* __restrict__ csA,
                                                   float* __restrict__ csB,
                                                   float* __restrict__ csAz,
                                                   float* __restrict__ csBz) {
  int hd = blockIdx.x;
  int t = threadIdx.x, w = t >> 6, lane = t & 63;
  __shared__ float pA[16][64], pB[16][64];
  __shared__ float pAz[16], pBz[16];
  const float* tsh = ts + (size_t)hd * N;
  const int* pmh = perm + (size_t)hd * N;
  float tm = tsh[N - 1];
  float rA[16], rB[16], rAz[16], rBz[16];
  for (int cc = 0; cc < 16; ++cc) {
    int c = w * 16 + cc, r0 = c * 16;
    // lane-parallel exps: lanes 0-15 hold eA_r, lanes 16-31 hold eB_r
    float tvv = tsh[r0 + (lane & 15)];
    float ev = expf((lane < 16 ? ALPHA : 1.f) * (tvv - tm));
    int pvv = pmh[r0 + (lane & 15)];
    float sA = 0.f, sB = 0.f, zA = 0.f, zB = 0.f;
#pragma unroll
    for (int r = 0; r < 16; ++r) {
      float eA = __shfl(ev, r);
      float eB = __shfl(ev, 16 + r);
      int p = __shfl(pvv, r);
      float hv = bf2f(h1b[((size_t)hd * N + p) * NHID + lane]);
      sA += eA * hv; sB += eB * hv; zA += eA; zB += eB;
    }
    rA[cc] = sA; rB[cc] = sB; rAz[cc] = zA; rBz[cc] = zB;
  }
  float tA = 0.f, tB = 0.f, tAz = 0.f, tBz = 0.f;
#pragma unroll
  for (int cc = 0; cc < 16; ++cc) { tA += rA[cc]; tB += rB[cc]; tAz += rAz[cc]; tBz += rBz[cc]; }
  pA[w][lane] = tA; pB[w][lane] = tB;
  if (lane == 0) { pAz[w] = tAz; pBz[w] = tBz; }
  __syncthreads();
  float bA = 0.f, bAz = 0.f, bB = 0.f, bBz = 0.f;
  for (int w2 = 0; w2 < w; ++w2) { bA += pA[w2][lane]; bAz += pAz[w2]; }
  for (int w2 = w + 1; w2 < 16; ++w2) { bB += pB[w2][lane]; bBz += pBz[w2]; }
  float run = bA, runz = bAz;
#pragma unroll
  for (int cc = 0; cc < 16; ++cc) {
    int c = w * 16 + cc;
    csA[((size_t)hd * NC + c) * NHID + lane] = run; run += rA[cc];
    if (lane == 0) { csAz[hd * NC + c] = runz; }
    runz += rAz[cc];
  }
  run = bB; runz = bBz;
#pragma unroll
  for (int cc = 15; cc >= 0; --cc) {
    int c = w * 16 + cc;
    csB[((size_t)hd * NC + c) * NHID + lane] = run; run += rB[cc];
    if (lane == 0) { csBz[hd * NC + c] = runz; }
    runz += rBz[cc];
  }
}

// ---------------------------------------------------------------------------
// K6: layer-1 combine. Precomputed split-k (no search, no staging); chunk
// bases + in-chunk rebuild (16 terms). 16 rows/block (4/wave). bf16 xc out.
// ---------------------------------------------------------------------------
__global__ __launch_bounds__(256) void k_combine1(const float* __restrict__ ssrc,
                                                  const float* __restrict__ ts,
                                                  const int* __restrict__ perm,
                                                  const int* __restrict__ ksp,
                                                  const unsigned short* __restrict__ h1b,
                                                  const float* __restrict__ csA,
                                                  const float* __restrict__ csB,
                                                  const float* __restrict__ csAz,
                                                  const float* __restrict__ csBz,
                                                  unsigned short* __restrict__ xcb) {
  int hd = blockIdx.x >> 8;
  int base = (blockIdx.x & 255) * 16;
  int w = threadIdx.x >> 6, lane = threadIdx.x & 63;
  const float* tsh = ts + (size_t)hd * N;
  float tm = tsh[N - 1];
  for (int it = 0; it < 4; ++it) {
    int i = base + w * 4 + it;
    float s = ssrc[(size_t)hd * N + i];
    int k = ksp[(size_t)hd * N + i];
    int c = k >> 4; if (c > NC - 1) c = NC - 1;
    int c0 = c * 16;
    float v = s + tm;
    float m = fmaxf(v, ALPHA * v);
    float wA = expf(ALPHA * v - m), wB = expf(v - m);
    size_t cb = (size_t)hd * NC + c;
    float numA = csA[cb * NHID + lane];
    float numB = csB[cb * NHID + lane];
    float zA = csAz[cb], zB = csBz[cb];
    int r15 = lane & 15;
    float tvv = tsh[c0 + r15];
    int pvv = perm[(size_t)hd * N + c0 + r15];
    float ev = expf(((c0 + r15) < k ? ALPHA : 1.f) * (tvv - tm));
#pragma unroll
    for (int r = 0; r < 16; ++r) {
      float e = __shfl(ev, r);
      int p = __shfl(pvv, r);
      float hv = bf2f(h1b[((size_t)hd * N + p) * NHID + lane]);
      bool isA = (c0 + r) < k;
      if (isA) { numA += e * hv; zA += e; } else { numB += e * hv; zB += e; }
    }
    float Z = wA * zA + wB * zB;
    float f = (wA * numA + wB * numB) / Z;
    float e2 = f > 0.f ? f : expf(f) - 1.f;
    xcb[(size_t)i * (NHEADS * NHID) + hd * NHID + lane] = f2bf(e2);
  }
}

// ---------------------------------------------------------------------------
// K7: h2 = xc @ Wo via MFMA (M=4096,N=16,K=512) + fused layer-2 scores.
// ---------------------------------------------------------------------------
__global__ __launch_bounds__(256) void k_gemm2(const unsigned short* __restrict__ xcb,
                                               const unsigned short* __restrict__ Wt2,
                                               const float* __restrict__ ao,
                                               float* __restrict__ h2,
                                               float* __restrict__ ssrc,
                                               float* __restrict__ sdst) {
  const int t = threadIdx.x;
  const int w = t >> 6, lane = t & 63;
  const int lr = lane & 15, kg = lane >> 4;
  const int i0 = blockIdx.x * 64 + w * 16;
  f32x4 acc = (f32x4){0.f, 0.f, 0.f, 0.f};
  const unsigned short* arow = xcb + (size_t)(i0 + lr) * NFEAT;
  const unsigned short* brow = Wt2 + (size_t)lr * NFEAT;
#pragma unroll
  for (int k0 = 0; k0 < NFEAT; k0 += 32) {
    bf16x8 af = __builtin_bit_cast(bf16x8, *(const uint4*)(arow + k0 + kg * 8));
    bf16x8 bv = __builtin_bit_cast(bf16x8, *(const uint4*)(brow + k0 + kg * 8));
    acc = __builtin_amdgcn_mfma_f32_16x16x32_bf16(af, bv, acc, 0, 0, 0);
  }
  float aS = ao[lr], aD = ao[16 + lr];
#pragma unroll
  for (int reg = 0; reg < 4; ++reg) {
    int row = i0 + kg * 4 + reg;
    h2[(size_t)row * NCLASS + lr] = acc[reg];
    float ps = acc[reg] * aS, pd = acc[reg] * aD;
#pragma unroll
    for (int m = 1; m < 16; m <<= 1) { ps += __shfl_xor(ps, m); pd += __shfl_xor(pd, m); }
    if (lr == 0) { ssrc[row] = ps; sdst[row] = pd; }
  }
}

// ---------------------------------------------------------------------------
// K8: fused chunksum + scan, layer 2 (F=16). 1 block x 256 thr, 16 groups
// of 16 lanes; 16 chunks/group in registers; one barrier; scan; write.
// ---------------------------------------------------------------------------
__global__ __launch_bounds__(256) void k_sumscan2(const float* __restrict__ ts,
                                                  const int* __restrict__ perm,
                                                  const float* __restrict__ h2,
                                                  float* __restrict__ csA,
                                                  float* __restrict__ csB,
                                                  float* __restrict__ csAz,
                                                  float* __restrict__ csBz) {
  int t = threadIdx.x, g = t >> 4, cl = t & 15;
  __shared__ float pA[16][16], pB[16][16];
  __shared__ float pAz[16], pBz[16];
  float tm = ts[N - 1];
  float rA[16], rB[16], rAz[16], rBz[16];
  for (int cc = 0; cc < 16; ++cc) {
    int c = g * 16 + cc, r0 = c * 16;
    float tvv = ts[r0 + cl];
    float eAv = expf(ALPHA * (tvv - tm));
    float eBv = expf(tvv - tm);
    int pvv = perm[r0 + cl];
    float sA = 0.f, sB = 0.f, zA = 0.f, zB = 0.f;
#pragma unroll
    for (int r = 0; r < 16; ++r) {
      float eA = __shfl(eAv, r, 16);
      float eB = __shfl(eBv, r, 16);
      int p = __shfl(pvv, r, 16);
      float hv = h2[(size_t)p * NCLASS + cl];
      sA += eA * hv; sB += eB * hv; zA += eA; zB += eB;
    }
    rA[cc] = sA; rB[cc] = sB; rAz[cc] = zA; rBz[cc] = zB;
  }
  float tA = 0.f, tB = 0.f, tAz = 0.f, tBz = 0.f;
#pragma unroll
  for (int cc = 0; cc < 16; ++cc) { tA += rA[cc]; tB += rB[cc]; tAz += rAz[cc]; tBz += rBz[cc]; }
  pA[g][cl] = tA; pB[g][cl] = tB;
  if (cl == 0) { pAz[g] = tAz; pBz[g] = tBz; }
  __syncthreads();
  float bA = 0.f, bAz = 0.f, bB = 0.f, bBz = 0.f;
  for (int g2 = 0; g2 < g; ++g2) { bA += pA[g2][cl]; bAz += pAz[g2]; }
  for (int g2 = g + 1; g2 < 16; ++g2) { bB += pB[g2][cl]; bBz += pBz[g2]; }
  float run = bA, runz = bAz;
#pragma unroll
  for (int cc = 0; cc < 16; ++cc) {
    int c = g * 16 + cc;
    csA[(size_t)c * NCLASS + cl] = run; run += rA[cc];
    if (cl == 0) { csAz[c] = runz; }
    runz += rAz[cc];
  }
  run = bB; runz = bBz;
#pragma unroll
  for (int cc = 15; cc >= 0; --cc) {
    int c = g * 16 + cc;
    csB[(size_t)c * NCLASS + cl] = run; run += rB[cc];
    if (cl == 0) { csBz[c] = runz; }
    runz += rBz[cc];
  }
}

// ---------------------------------------------------------------------------
// K9: layer-2 combine (split-k precomputed) + ELU + log_softmax.
// ---------------------------------------------------------------------------
__global__ __launch_bounds__(256) void k_combine2(const float* __restrict__ ssrc,
                                                  const float* __restrict__ ts,
                                                  const int* __restrict__ perm,
                                                  const int* __restrict__ ksp,
                                                  const float* __restrict__ h2,
                                                  const float* __restrict__ csA,
                                                  const float* __restrict__ csB,
                                                  const float* __restrict__ csAz,
                                                  const float* __restrict__ csBz,
                                                  float* __restrict__ out) {
  int g = threadIdx.x >> 4, cl = threadIdx.x & 15;
  int i = blockIdx.x * 16 + g;
  float tm = ts[N - 1];
  float s = ssrc[i];
  int k = ksp[i];
  int c = k >> 4; if (c > NC - 1) c = NC - 1;
  int c0 = c * 16;
  float v = s + tm;
  float m = fmaxf(v, ALPHA * v);
  float wA = expf(ALPHA * v - m), wB = expf(v - m);
  float numA = csA[(size_t)c * NCLASS + cl];
  float numB = csB[(size_t)c * NCLASS + cl];
  float zA = csAz[c], zB = csBz[c];
  float tvv = ts[c0 + cl];
  int pvv = perm[c0 + cl];
  float ev = expf(((c0 + cl) < k ? ALPHA : 1.f) * (tvv - tm));
#pragma unroll
  for (int r = 0; r < 16; ++r) {
    float e = __shfl(ev, r, 16);
    int p = __shfl(pvv, r, 16);
    float hv = h2[(size_t)p * NCLASS + cl];
    bool isA = (c0 + r) < k;
    if (isA) { numA += e * hv; zA += e; } else { numB += e * hv; zB += e; }
  }
  float Z = wA * zA + wB * zB;
  float f = (wA * numA + wB * numB) / Z;
  float o = f > 0.f ? f : expf(f) - 1.f;
  float mx = o;
#pragma unroll
  for (int mk = 1; mk < 16; mk <<= 1) mx = fmaxf(mx, __shfl_xor(mx, mk, 16));
  float ex = expf(o - mx);
  float sum = ex;
#pragma unroll
  for (int mk = 1; mk < 16; mk <<= 1) sum += __shfl_xor(sum, mk, 16);
  out[(size_t)i * NCLASS + cl] = o - mx - logf(sum);
}

// ---------------------------------------------------------------------------
extern "C" void kernel_launch(void* const* d_in, const int* in_sizes, int n_in,
                              void* d_out, int out_size, void* d_ws, size_t ws_size,
                              hipStream_t stream) {
  const float* x  = (const float*)d_in[0];
  const float* Wh = (const float*)d_in[1];
  const float* ah = (const float*)d_in[2];
  const float* Wo = (const float*)d_in[3];
  const float* ao = (const float*)d_in[4];
  float* out = (float*)d_out;

  char* base = (char*)d_ws;
  size_t off = 0;
  auto alloc_f = [&](size_t n) -> float* {
    float* p = (float*)(base + off);
    off = (off + n * sizeof(float) + 255) & ~(size_t)255;
    return p;
  };
  auto alloc_i = [&](size_t n) -> int* {
    int* p = (int*)(base + off);
    off = (off + n * sizeof(int) + 255) & ~(size_t)255;
    return p;
  };
  auto alloc_u16 = [&](size_t n) -> unsigned short* {
    unsigned short* p = (unsigned short*)(base + off);
    off = (off + n * sizeof(unsigned short) + 255) & ~(size_t)255;
    return p;
  };

  unsigned short* xbf = alloc_u16((size_t)N * NFEAT);
  unsigned short* Wt  = alloc_u16((size_t)NHEADS * NHID * NFEAT);
  unsigned short* Wt2 = alloc_u16((size_t)NCLASS * NFEAT);
  unsigned short* h1b = alloc_u16((size_t)NHEADS * N * NHID);
  float* ssrc1 = alloc_f((size_t)NHEADS * N);
  float* sdst1 = alloc_f((size_t)NHEADS * N);
  float* ts1   = alloc_f((size_t)NHEADS * N);
  int*   perm1 = alloc_i((size_t)NHEADS * N);
  int*   ksp1  = alloc_i((size_t)NHEADS * N);
  float* csA1  = alloc_f((size_t)NHEADS * NC * NHID);
  float* csB1  = alloc_f((size_t)NHEADS * NC * NHID);
  float* csAz1 = alloc_f(NHEADS * NC);
  float* csBz1 = alloc_f(NHEADS * NC);
  unsigned short* xcb = alloc_u16((size_t)N * NHEADS * NHID);
  float* h2    = alloc_f((size_t)N * NCLASS);
  float* ssrc2 = alloc_f(N);
  float* sdst2 = alloc_f(N);
  float* ts2   = alloc_f(N);
  int*   perm2 = alloc_i(N);
  int*   ksp2  = alloc_i(N);
  float* csA2  = alloc_f((size_t)NC * NCLASS);
  float* csB2  = alloc_f((size_t)NC * NCLASS);
  float* csAz2 = alloc_f(NC);
  float* csBz2 = alloc_f(NC);

  if (off > ws_size) return;

  hipLaunchKernelGGL(k_pack, dim3(2113), dim3(256), 0, stream, x, Wh, Wo, xbf, Wt, Wt2);

  // ---- Layer 1 ----
  hipLaunchKernelGGL(k_gemm_h, dim3(N / 128, NHEADS), dim3(256), 0, stream, xbf, Wt, ah, h1b, ssrc1, sdst1);
  hipLaunchKernelGGL(k_rank, dim3(64, NHEADS), dim3(256), 0, stream, sdst1, ssrc1, ts1, perm1, ksp1);
  hipLaunchKernelGGL(k_sumscan1, dim3(NHEADS), dim3(1024), 0, stream, ts1, perm1, h1b, csA1, csB1, csAz1, csBz1);
  hipLaunchKernelGGL(k_combine1, dim3(NHEADS * 256), dim3(256), 0, stream, ssrc1, ts1, perm1, ksp1, h1b, csA1, csB1, csAz1, csBz1, xcb);

  // ---- Layer 2 ----
  hipLaunchKernelGGL(k_gemm2, dim3(N / 64), dim3(256), 0, stream, xcb, Wt2, ao, h2, ssrc2, sdst2);
  hipLaunchKernelGGL(k_rank, dim3(64, 1), dim3(256), 0, stream, sdst2, ssrc2, ts2, perm2, ksp2);
  hipLaunchKernelGGL(k_sumscan2, dim3(1), dim3(256), 0, stream, ts2, perm2, h2, csA2, csB2, csAz2, csBz2);
  hipLaunchKernelGGL(k_combine2, dim3(N / 16), dim3(256), 0, stream, ssrc2, ts2, perm2, ksp2, h2, csA2, csB2, csAz2, csBz2, out);
}

// Round 9
// 128.933 us; speedup vs baseline: 4.4983x; 1.8362x over previous
//
#include <hip/hip_runtime.h>
#include <math.h>

#define N 4096
#define NFEAT 512
#define NHID 64
#define NCLASS 16
#define NHEADS 8
#define ALPHA 0.2f
#define NC 256   // chunks per head (16 rows each)

typedef __attribute__((ext_vector_type(8))) short bf16x8;
typedef __attribute__((ext_vector_type(4))) float f32x4;

__device__ inline unsigned short f2bf(float f) {
  unsigned u = __float_as_uint(f);
  unsigned r = u + 0x7fffu + ((u >> 16) & 1u);  // RNE
  return (unsigned short)(r >> 16);
}
__device__ inline float bf2f(unsigned short u) {
  return __uint_as_float(((unsigned)u) << 16);
}
__device__ inline unsigned mono(float f) {
  unsigned u = __float_as_uint(f);
  return (u & 0x80000000u) ? ~u : (u | 0x80000000u);
}

// ---------------------------------------------------------------------------
// P0: pack. blocks [0,2048): x->bf16; [2048,2112): Wt=bf16(Wh^T); 2112: Wt2.
// ---------------------------------------------------------------------------
__global__ __launch_bounds__(256) void k_pack(const float* __restrict__ x,
                                              const float* __restrict__ Wh,
                                              const float* __restrict__ Wo,
                                              unsigned short* __restrict__ xb,
                                              unsigned short* __restrict__ Wt,
                                              unsigned short* __restrict__ Wt2) {
  int b = blockIdx.x;
  if (b < 2048) {
    int i = (b * 256 + threadIdx.x) * 4;
    float4 v = *(const float4*)(x + i);
    ushort4 o;
    o.x = f2bf(v.x); o.y = f2bf(v.y); o.z = f2bf(v.z); o.w = f2bf(v.w);
    *(ushort4*)(xb + i) = o;
  } else if (b < 2112) {
    int idx = b - 2048;
    int kt = idx & 7, hd = idx >> 3;
    __shared__ float ld[64][65];
    const float* src = Wh + ((size_t)hd * NFEAT + kt * 64) * NHID;
    int r = threadIdx.x >> 2, c0 = (threadIdx.x & 3) * 16;
#pragma unroll
    for (int j = 0; j < 4; ++j) {
      float4 v = *(const float4*)(src + (size_t)r * NHID + c0 + j * 4);
      ld[r][c0 + j * 4 + 0] = v.x; ld[r][c0 + j * 4 + 1] = v.y;
      ld[r][c0 + j * 4 + 2] = v.z; ld[r][c0 + j * 4 + 3] = v.w;
    }
    __syncthreads();
    int n = threadIdx.x >> 2, kq = threadIdx.x & 3;
    unsigned short tmp[16];
#pragma unroll
    for (int j = 0; j < 16; ++j) tmp[j] = f2bf(ld[kq * 16 + j][n]);
    unsigned short* dst = Wt + ((size_t)hd * 64 + n) * NFEAT + kt * 64 + kq * 16;
    ((uint4*)dst)[0] = *(uint4*)tmp;
    ((uint4*)dst)[1] = *(uint4*)(tmp + 8);
  } else {
    for (int e = threadIdx.x; e < NFEAT * NCLASS; e += 256) {
      int n = e & 15, k = e >> 4;
      Wt2[(size_t)n * NFEAT + k] = f2bf(Wo[(size_t)k * NCLASS + n]);
    }
  }
}

// ---------------------------------------------------------------------------
// K1: MFMA bf16 GEMM h = x @ Wh per head, 128x64 tile, 4 waves, fused scores.
// h stored bf16.
// ---------------------------------------------------------------------------
__global__ __launch_bounds__(256) void k_gemm_h(const unsigned short* __restrict__ xb,
                                                const unsigned short* __restrict__ Wt,
                                                const float* __restrict__ ah,
                                                unsigned short* __restrict__ h1b,
                                                float* __restrict__ ssrc,
                                                float* __restrict__ sdst) {
  const int hd = blockIdx.y;
  const int i0 = blockIdx.x * 128;
  const int t = threadIdx.x;
  const int w = t >> 6, lane = t & 63;
  const int lr = lane & 15, kg = lane >> 4;
  const int wm = (w & 1) * 64, wn = (w >> 1) * 32;
  __shared__ uint4 Als[128][4];
  __shared__ uint4 Bls[64][4];
  __shared__ float sredS[128][2];
  __shared__ float sredD[128][2];
  const unsigned short* xrow = xb + (size_t)i0 * NFEAT;
  const unsigned short* wrow = Wt + (size_t)hd * 64 * NFEAT;

  f32x4 acc[4][2];
#pragma unroll
  for (int a = 0; a < 4; ++a)
#pragma unroll
    for (int b = 0; b < 2; ++b) acc[a][b] = (f32x4){0.f, 0.f, 0.f, 0.f};

  const int ra = t >> 1, ua = (t & 1) * 2;
  const int rb = t >> 2, ub = t & 3;
  for (int k0 = 0; k0 < NFEAT; k0 += 32) {
    uint4 qa0 = *(const uint4*)(xrow + (size_t)ra * NFEAT + k0 + ua * 8);
    uint4 qa1 = *(const uint4*)(xrow + (size_t)ra * NFEAT + k0 + ua * 8 + 8);
    uint4 qb  = *(const uint4*)(wrow + (size_t)rb * NFEAT + k0 + ub * 8);
    Als[ra][(ua) ^ (ra & 3)] = qa0;
    Als[ra][(ua + 1) ^ (ra & 3)] = qa1;
    Bls[rb][ub ^ (rb & 3)] = qb;
    __syncthreads();
    bf16x8 af[4], bfv[2];
#pragma unroll
    for (int mb = 0; mb < 4; ++mb) {
      int row = wm + mb * 16 + lr;
      af[mb] = __builtin_bit_cast(bf16x8, Als[row][kg ^ (row & 3)]);
    }
#pragma unroll
    for (int nb = 0; nb < 2; ++nb) {
      int col = wn + nb * 16 + lr;
      bfv[nb] = __builtin_bit_cast(bf16x8, Bls[col][kg ^ (col & 3)]);
    }
#pragma unroll
    for (int mb = 0; mb < 4; ++mb)
#pragma unroll
      for (int nb = 0; nb < 2; ++nb)
        acc[mb][nb] = __builtin_amdgcn_mfma_f32_16x16x32_bf16(af[mb], bfv[nb], acc[mb][nb], 0, 0, 0);
    __syncthreads();
  }

  unsigned short* hout = h1b + ((size_t)hd * N + i0) * NHID;
#pragma unroll
  for (int mb = 0; mb < 4; ++mb)
#pragma unroll
    for (int nb = 0; nb < 2; ++nb) {
      int rbase = wm + mb * 16 + kg * 4;
      int col = wn + nb * 16 + lr;
#pragma unroll
      for (int reg = 0; reg < 4; ++reg)
        hout[(size_t)(rbase + reg) * NHID + col] = f2bf(acc[mb][nb][reg]);
    }

  float aS[2], aD[2];
#pragma unroll
  for (int nb = 0; nb < 2; ++nb) {
    aS[nb] = ah[hd * 128 + wn + nb * 16 + lr];
    aD[nb] = ah[hd * 128 + 64 + wn + nb * 16 + lr];
  }
#pragma unroll
  for (int mb = 0; mb < 4; ++mb)
#pragma unroll
    for (int reg = 0; reg < 4; ++reg) {
      float ps = acc[mb][0][reg] * aS[0] + acc[mb][1][reg] * aS[1];
      float pd = acc[mb][0][reg] * aD[0] + acc[mb][1][reg] * aD[1];
#pragma unroll
      for (int m = 1; m < 16; m <<= 1) { ps += __shfl_xor(ps, m); pd += __shfl_xor(pd, m); }
      if (lr == 0) {
        int rl = wm + mb * 16 + kg * 4 + reg;
        sredS[rl][w >> 1] = ps;
        sredD[rl][w >> 1] = pd;
      }
    }
  __syncthreads();
  if (t < 128) {
    ssrc[(size_t)hd * N + i0 + t] = sredS[t][0] + sredS[t][1];
    sdst[(size_t)hd * N + i0 + t] = sredD[t][0] + sredD[t][1];
  }
}

// ---------------------------------------------------------------------------
// K4: ballot rank + per-row split-k. u32 keys (monotone 20 bits | index).
// ---------------------------------------------------------------------------
__global__ __launch_bounds__(256) void k_rank(const float* __restrict__ t,
                                              const float* __restrict__ ssrc,
                                              float* __restrict__ ts,
                                              int* __restrict__ perm,
                                              int* __restrict__ ksp) {
  int hd = blockIdx.y;
  const float* th = t + (size_t)hd * N;
  __shared__ unsigned skey[N];
  int tid = threadIdx.x;
  for (int i = tid; i < N; i += 256)
    skey[i] = (mono(th[i]) & 0xFFFFF000u) | (unsigned)i;
  __syncthreads();
  int wv = tid >> 6, lane = tid & 63;
  int jbase = blockIdx.x * 64 + wv * 16;
  unsigned kj[16], qk[16];
  int cnt[16], cq[16];
#pragma unroll
  for (int jj = 0; jj < 16; ++jj) {
    kj[jj] = skey[jbase + jj];
    qk[jj] = (mono(-ssrc[(size_t)hd * N + jbase + jj]) & 0xFFFFF000u) | 0xFFFu;
    cnt[jj] = 0; cq[jj] = 0;
  }
  for (int c = 0; c < N; c += 64) {
    unsigned key = skey[c + lane];
#pragma unroll
    for (int jj = 0; jj < 16; ++jj) {
      cnt[jj] += __popcll(__ballot(key < kj[jj]));
      cq[jj]  += __popcll(__ballot(key < qk[jj]));
    }
  }
  int myc = 0, myq = 0;
#pragma unroll
  for (int jj = 0; jj < 16; ++jj)
    if (lane == jj) { myc = cnt[jj]; myq = cq[jj]; }
  if (lane < 16) {
    int j = jbase + lane;
    ts[(size_t)hd * N + myc] = th[j];
    perm[(size_t)hd * N + myc] = j;
    ksp[(size_t)hd * N + j] = myq;
  }
}

// ---------------------------------------------------------------------------
// K5a: chunksum layer 1 (WIDE grid for the gather). One wave per 16-row
// chunk; grid (64, 8) x 256 thr = 2048 waves.
// ---------------------------------------------------------------------------
__global__ __launch_bounds__(256) void k_chunksum1(const float* __restrict__ ts,
                                                   const int* __restrict__ perm,
                                                   const unsigned short* __restrict__ h1b,
                                                   float* __restrict__ csA,
                                                   float* __restrict__ csB,
                                                   float* __restrict__ csAz,
                                                   float* __restrict__ csBz) {
  int hd = blockIdx.y, lane = threadIdx.x & 63;
  int c = blockIdx.x * 4 + (threadIdx.x >> 6);
  int r0 = c * 16;
  float tm = ts[(size_t)hd * N + N - 1];
  // lanes 0-15 compute eA, lanes 16-31 eB (same t values)
  float tvv = ts[(size_t)hd * N + r0 + (lane & 15)];
  float ev = expf((lane < 16 ? ALPHA : 1.f) * (tvv - tm));
  int pvv = perm[(size_t)hd * N + r0 + (lane & 15)];
  float sA = 0.f, sB = 0.f, zA = 0.f, zB = 0.f;
#pragma unroll
  for (int r = 0; r < 16; ++r) {
    float eA = __shfl(ev, r);
    float eB = __shfl(ev, 16 + r);
    int p = __shfl(pvv, r);
    float hv = bf2f(h1b[((size_t)hd * N + p) * NHID + lane]);
    sA += eA * hv; sB += eB * hv; zA += eA; zB += eB;
  }
  csA[((size_t)hd * NC + c) * NHID + lane] = sA;
  csB[((size_t)hd * NC + c) * NHID + lane] = sB;
  if (lane == 0) { csAz[hd * NC + c] = zA; csBz[hd * NC + c] = zB; }
}

// ---------------------------------------------------------------------------
// K5b: scan-only layer 1 (narrow; no gather). 8 blocks x 1024 thr.
// Wave w holds 16 chunk-sums in regs; barrier; in-register exclusive scan.
// csA <- prefix-before-chunk, csB <- suffix-after-chunk.
// ---------------------------------------------------------------------------
__global__ __launch_bounds__(1024) void k_chunkscan1(float* __restrict__ csA,
                                                     float* __restrict__ csB,
                                                     float* __restrict__ csAz,
                                                     float* __restrict__ csBz) {
  int hd = blockIdx.x;
  int t = threadIdx.x, w = t >> 6, lane = t & 63;
  __shared__ float pA[16][64], pB[16][64];
  __shared__ float pAz[16], pBz[16];
  float rA[16], rB[16], rAz[16], rBz[16];
#pragma unroll
  for (int cc = 0; cc < 16; ++cc) {
    int c = w * 16 + cc;
    rA[cc] = csA[((size_t)hd * NC + c) * NHID + lane];
    rB[cc] = csB[((size_t)hd * NC + c) * NHID + lane];
    rAz[cc] = csAz[hd * NC + c];
    rBz[cc] = csBz[hd * NC + c];
  }
  float tA = 0.f, tB = 0.f, tAz = 0.f, tBz = 0.f;
#pragma unroll
  for (int cc = 0; cc < 16; ++cc) { tA += rA[cc]; tB += rB[cc]; tAz += rAz[cc]; tBz += rBz[cc]; }
  pA[w][lane] = tA; pB[w][lane] = tB;
  if (lane == 0) { pAz[w] = tAz; pBz[w] = tBz; }
  __syncthreads();
  float bA = 0.f, bAz = 0.f, bB = 0.f, bBz = 0.f;
  for (int w2 = 0; w2 < w; ++w2) { bA += pA[w2][lane]; bAz += pAz[w2]; }
  for (int w2 = w + 1; w2 < 16; ++w2) { bB += pB[w2][lane]; bBz += pBz[w2]; }
  float run = bA, runz = bAz;
#pragma unroll
  for (int cc = 0; cc < 16; ++cc) {
    int c = w * 16 + cc;
    csA[((size_t)hd * NC + c) * NHID + lane] = run; run += rA[cc];
    if (lane == 0) csAz[hd * NC + c] = runz;
    runz += rAz[cc];
  }
  run = bB; runz = bBz;
#pragma unroll
  for (int cc = 15; cc >= 0; --cc) {
    int c = w * 16 + cc;
    csB[((size_t)hd * NC + c) * NHID + lane] = run; run += rB[cc];
    if (lane == 0) csBz[hd * NC + c] = runz;
    runz += rBz[cc];
  }
}

// ---------------------------------------------------------------------------
// K6: layer-1 combine. Precomputed split-k; chunk bases + 16-term rebuild.
// ---------------------------------------------------------------------------
__global__ __launch_bounds__(256) void k_combine1(const float* __restrict__ ssrc,
                                                  const float* __restrict__ ts,
                                                  const int* __restrict__ perm,
                                                  const int* __restrict__ ksp,
                                                  const unsigned short* __restrict__ h1b,
                                                  const float* __restrict__ csA,
                                                  const float* __restrict__ csB,
                                                  const float* __restrict__ csAz,
                                                  const float* __restrict__ csBz,
                                                  unsigned short* __restrict__ xcb) {
  int hd = blockIdx.x >> 8;
  int base = (blockIdx.x & 255) * 16;
  int w = threadIdx.x >> 6, lane = threadIdx.x & 63;
  const float* tsh = ts + (size_t)hd * N;
  float tm = tsh[N - 1];
  for (int it = 0; it < 4; ++it) {
    int i = base + w * 4 + it;
    float s = ssrc[(size_t)hd * N + i];
    int k = ksp[(size_t)hd * N + i];
    int c = k >> 4; if (c > NC - 1) c = NC - 1;
    int c0 = c * 16;
    float v = s + tm;
    float m = fmaxf(v, ALPHA * v);
    float wA = expf(ALPHA * v - m), wB = expf(v - m);
    size_t cb = (size_t)hd * NC + c;
    float numA = csA[cb * NHID + lane];
    float numB = csB[cb * NHID + lane];
    float zA = csAz[cb], zB = csBz[cb];
    int r15 = lane & 15;
    float tvv = tsh[c0 + r15];
    int pvv = perm[(size_t)hd * N + c0 + r15];
    float ev = expf(((c0 + r15) < k ? ALPHA : 1.f) * (tvv - tm));
#pragma unroll
    for (int r = 0; r < 16; ++r) {
      float e = __shfl(ev, r);
      int p = __shfl(pvv, r);
      float hv = bf2f(h1b[((size_t)hd * N + p) * NHID + lane]);
      bool isA = (c0 + r) < k;
      if (isA) { numA += e * hv; zA += e; } else { numB += e * hv; zB += e; }
    }
    float Z = wA * zA + wB * zB;
    float f = (wA * numA + wB * numB) / Z;
    float e2 = f > 0.f ? f : expf(f) - 1.f;
    xcb[(size_t)i * (NHEADS * NHID) + hd * NHID + lane] = f2bf(e2);
  }
}

// ---------------------------------------------------------------------------
// K7: h2 = xc @ Wo via MFMA (M=4096,N=16,K=512) + fused layer-2 scores.
// ---------------------------------------------------------------------------
__global__ __launch_bounds__(256) void k_gemm2(const unsigned short* __restrict__ xcb,
                                               const unsigned short* __restrict__ Wt2,
                                               const float* __restrict__ ao,
                                               float* __restrict__ h2,
                                               float* __restrict__ ssrc,
                                               float* __restrict__ sdst) {
  const int t = threadIdx.x;
  const int w = t >> 6, lane = t & 63;
  const int lr = lane & 15, kg = lane >> 4;
  const int i0 = blockIdx.x * 64 + w * 16;
  f32x4 acc = (f32x4){0.f, 0.f, 0.f, 0.f};
  const unsigned short* arow = xcb + (size_t)(i0 + lr) * NFEAT;
  const unsigned short* brow = Wt2 + (size_t)lr * NFEAT;
#pragma unroll
  for (int k0 = 0; k0 < NFEAT; k0 += 32) {
    bf16x8 af = __builtin_bit_cast(bf16x8, *(const uint4*)(arow + k0 + kg * 8));
    bf16x8 bv = __builtin_bit_cast(bf16x8, *(const uint4*)(brow + k0 + kg * 8));
    acc = __builtin_amdgcn_mfma_f32_16x16x32_bf16(af, bv, acc, 0, 0, 0);
  }
  float aS = ao[lr], aD = ao[16 + lr];
#pragma unroll
  for (int reg = 0; reg < 4; ++reg) {
    int row = i0 + kg * 4 + reg;
    h2[(size_t)row * NCLASS + lr] = acc[reg];
    float ps = acc[reg] * aS, pd = acc[reg] * aD;
#pragma unroll
    for (int m = 1; m < 16; m <<= 1) { ps += __shfl_xor(ps, m); pd += __shfl_xor(pd, m); }
    if (lr == 0) { ssrc[row] = ps; sdst[row] = pd; }
  }
}

// ---------------------------------------------------------------------------
// K8a: chunksum layer 2 (wide). One wave per chunk (lanes 0-15 + 16-31 for
// eA/eB trick over F=16). grid 64 x 256 thr.
// ---------------------------------------------------------------------------
__global__ __launch_bounds__(256) void k_chunksum2(const float* __restrict__ ts,
                                                   const int* __restrict__ perm,
                                                   const float* __restrict__ h2,
                                                   float* __restrict__ csA,
                                                   float* __restrict__ csB,
                                                   float* __restrict__ csAz,
                                                   float* __restrict__ csBz) {
  int lane = threadIdx.x & 63;
  int c = blockIdx.x * 4 + (threadIdx.x >> 6);
  int r0 = c * 16, cl = lane & 15;
  float tm = ts[N - 1];
  float tvv = ts[r0 + cl];
  float ev = expf((lane < 16 ? ALPHA : 1.f) * (tvv - tm));
  int pvv = perm[r0 + cl];
  float sA = 0.f, sB = 0.f, zA = 0.f, zB = 0.f;
#pragma unroll
  for (int r = 0; r < 16; ++r) {
    float eA = __shfl(ev, r);
    float eB = __shfl(ev, 16 + r);
    int p = __shfl(pvv, r);
    float hv = (lane < 16) ? h2[(size_t)p * NCLASS + cl] : 0.f;
    sA += eA * hv; sB += eB * hv; zA += eA; zB += eB;
  }
  if (lane < 16) {
    csA[(size_t)c * NCLASS + cl] = sA;
    csB[(size_t)c * NCLASS + cl] = sB;
  }
  if (lane == 0) { csAz[c] = zA; csBz[c] = zB; }
}

// ---------------------------------------------------------------------------
// K8b: scan-only layer 2. 1 block x 256 thr (16 groups x 16 chunks, F=16).
// ---------------------------------------------------------------------------
__global__ __launch_bounds__(256) void k_chunkscan2(float* __restrict__ csA,
                                                    float* __restrict__ csB,
                                                    float* __restrict__ csAz,
                                                    float* __restrict__ csBz) {
  int t = threadIdx.x, g = t >> 4, cl = t & 15;
  __shared__ float pA[16][16], pB[16][16];
  __shared__ float pAz[16], pBz[16];
  float rA[16], rB[16], rAz[16], rBz[16];
#pragma unroll
  for (int cc = 0; cc < 16; ++cc) {
    int c = g * 16 + cc;
    rA[cc] = csA[(size_t)c * NCLASS + cl];
    rB[cc] = csB[(size_t)c * NCLASS + cl];
    rAz[cc] = csAz[c];
    rBz[cc] = csBz[c];
  }
  float tA = 0.f, tB = 0.f, tAz = 0.f, tBz = 0.f;
#pragma unroll
  for (int cc = 0; cc < 16; ++cc) { tA += rA[cc]; tB += rB[cc]; tAz += rAz[cc]; tBz += rBz[cc]; }
  pA[g][cl] = tA; pB[g][cl] = tB;
  if (cl == 0) { pAz[g] = tAz; pBz[g] = tBz; }
  __syncthreads();
  float bA = 0.f, bAz = 0.f, bB = 0.f, bBz = 0.f;
  for (int g2 = 0; g2 < g; ++g2) { bA += pA[g2][cl]; bAz += pAz[g2]; }
  for (int g2 = g + 1; g2 < 16; ++g2) { bB += pB[g2][cl]; bBz += pBz[g2]; }
  float run = bA, runz = bAz;
#pragma unroll
  for (int cc = 0; cc < 16; ++cc) {
    int c = g * 16 + cc;
    csA[(size_t)c * NCLASS + cl] = run; run += rA[cc];
    if (cl == 0) csAz[c] = runz;
    runz += rAz[cc];
  }
  run = bB; runz = bBz;
#pragma unroll
  for (int cc = 15; cc >= 0; --cc) {
    int c = g * 16 + cc;
    csB[(size_t)c * NCLASS + cl] = run; run += rB[cc];
    if (cl == 0) csBz[c] = runz;
    runz += rBz[cc];
  }
}

// ---------------------------------------------------------------------------
// K9: layer-2 combine (split-k precomputed) + ELU + log_softmax.
// ---------------------------------------------------------------------------
__global__ __launch_bounds__(256) void k_combine2(const float* __restrict__ ssrc,
                                                  const float* __restrict__ ts,
                                                  const int* __restrict__ perm,
                                                  const int* __restrict__ ksp,
                                                  const float* __restrict__ h2,
                                                  const float* __restrict__ csA,
                                                  const float* __restrict__ csB,
                                                  const float* __restrict__ csAz,
                                                  const float* __restrict__ csBz,
                                                  float* __restrict__ out) {
  int g = threadIdx.x >> 4, cl = threadIdx.x & 15;
  int i = blockIdx.x * 16 + g;
  float tm = ts[N - 1];
  float s = ssrc[i];
  int k = ksp[i];
  int c = k >> 4; if (c > NC - 1) c = NC - 1;
  int c0 = c * 16;
  float v = s + tm;
  float m = fmaxf(v, ALPHA * v);
  float wA = expf(ALPHA * v - m), wB = expf(v - m);
  float numA = csA[(size_t)c * NCLASS + cl];
  float numB = csB[(size_t)c * NCLASS + cl];
  float zA = csAz[c], zB = csBz[c];
  float tvv = ts[c0 + cl];
  int pvv = perm[c0 + cl];
  float ev = expf(((c0 + cl) < k ? ALPHA : 1.f) * (tvv - tm));
#pragma unroll
  for (int r = 0; r < 16; ++r) {
    float e = __shfl(ev, r, 16);
    int p = __shfl(pvv, r, 16);
    float hv = h2[(size_t)p * NCLASS + cl];
    bool isA = (c0 + r) < k;
    if (isA) { numA += e * hv; zA += e; } else { numB += e * hv; zB += e; }
  }
  float Z = wA * zA + wB * zB;
  float f = (wA * numA + wB * numB) / Z;
  float o = f > 0.f ? f : expf(f) - 1.f;
  float mx = o;
#pragma unroll
  for (int mk = 1; mk < 16; mk <<= 1) mx = fmaxf(mx, __shfl_xor(mx, mk, 16));
  float ex = expf(o - mx);
  float sum = ex;
#pragma unroll
  for (int mk = 1; mk < 16; mk <<= 1) sum += __shfl_xor(sum, mk, 16);
  out[(size_t)i * NCLASS + cl] = o - mx - logf(sum);
}

// ---------------------------------------------------------------------------
extern "C" void kernel_launch(void* const* d_in, const int* in_sizes, int n_in,
                              void* d_out, int out_size, void* d_ws, size_t ws_size,
                              hipStream_t stream) {
  const float* x  = (const float*)d_in[0];
  const float* Wh = (const float*)d_in[1];
  const float* ah = (const float*)d_in[2];
  const float* Wo = (const float*)d_in[3];
  const float* ao = (const float*)d_in[4];
  float* out = (float*)d_out;

  char* base = (char*)d_ws;
  size_t off = 0;
  auto alloc_f = [&](size_t n) -> float* {
    float* p = (float*)(base + off);
    off = (off + n * sizeof(float) + 255) & ~(size_t)255;
    return p;
  };
  auto alloc_i = [&](size_t n) -> int* {
    int* p = (int*)(base + off);
    off = (off + n * sizeof(int) + 255) & ~(size_t)255;
    return p;
  };
  auto alloc_u16 = [&](size_t n) -> unsigned short* {
    unsigned short* p = (unsigned short*)(base + off);
    off = (off + n * sizeof(unsigned short) + 255) & ~(size_t)255;
    return p;
  };

  unsigned short* xbf = alloc_u16((size_t)N * NFEAT);
  unsigned short* Wt  = alloc_u16((size_t)NHEADS * NHID * NFEAT);
  unsigned short* Wt2 = alloc_u16((size_t)NCLASS * NFEAT);
  unsigned short* h1b = alloc_u16((size_t)NHEADS * N * NHID);
  float* ssrc1 = alloc_f((size_t)NHEADS * N);
  float* sdst1 = alloc_f((size_t)NHEADS * N);
  float* ts1   = alloc_f((size_t)NHEADS * N);
  int*   perm1 = alloc_i((size_t)NHEADS * N);
  int*   ksp1  = alloc_i((size_t)NHEADS * N);
  float* csA1  = alloc_f((size_t)NHEADS * NC * NHID);
  float* csB1  = alloc_f((size_t)NHEADS * NC * NHID);
  float* csAz1 = alloc_f(NHEADS * NC);
  float* csBz1 = alloc_f(NHEADS * NC);
  unsigned short* xcb = alloc_u16((size_t)N * NHEADS * NHID);
  float* h2    = alloc_f((size_t)N * NCLASS);
  float* ssrc2 = alloc_f(N);
  float* sdst2 = alloc_f(N);
  float* ts2   = alloc_f(N);
  int*   perm2 = alloc_i(N);
  int*   ksp2  = alloc_i(N);
  float* csA2  = alloc_f((size_t)NC * NCLASS);
  float* csB2  = alloc_f((size_t)NC * NCLASS);
  float* csAz2 = alloc_f(NC);
  float* csBz2 = alloc_f(NC);

  if (off > ws_size) return;

  hipLaunchKernelGGL(k_pack, dim3(2113), dim3(256), 0, stream, x, Wh, Wo, xbf, Wt, Wt2);

  // ---- Layer 1 ----
  hipLaunchKernelGGL(k_gemm_h, dim3(N / 128, NHEADS), dim3(256), 0, stream, xbf, Wt, ah, h1b, ssrc1, sdst1);
  hipLaunchKernelGGL(k_rank, dim3(64, NHEADS), dim3(256), 0, stream, sdst1, ssrc1, ts1, perm1, ksp1);
  hipLaunchKernelGGL(k_chunksum1, dim3(64, NHEADS), dim3(256), 0, stream, ts1, perm1, h1b, csA1, csB1, csAz1, csBz1);
  hipLaunchKernelGGL(k_chunkscan1, dim3(NHEADS), dim3(1024), 0, stream, csA1, csB1, csAz1, csBz1);
  hipLaunchKernelGGL(k_combine1, dim3(NHEADS * 256), dim3(256), 0, stream, ssrc1, ts1, perm1, ksp1, h1b, csA1, csB1, csAz1, csBz1, xcb);

  // ---- Layer 2 ----
  hipLaunchKernelGGL(k_gemm2, dim3(N / 64), dim3(256), 0, stream, xcb, Wt2, ao, h2, ssrc2, sdst2);
  hipLaunchKernelGGL(k_rank, dim3(64, 1), dim3(256), 0, stream, sdst2, ssrc2, ts2, perm2, ksp2);
  hipLaunchKernelGGL(k_chunksum2, dim3(64), dim3(256), 0, stream, ts2, perm2, h2, csA2, csB2, csAz2, csBz2);
  hipLaunchKernelGGL(k_chunkscan2, dim3(1), dim3(256), 0, stream, csA2, csB2, csAz2, csBz2);
  hipLaunchKernelGGL(k_combine2, dim3(N / 16), dim3(256), 0, stream, ssrc2, ts2, perm2, ksp2, h2, csA2, csB2, csAz2, csBz2, out);
}